// Round 6
// baseline (399.501 us; speedup 1.0000x reference)
//
#include <hip/hip_runtime.h>

typedef unsigned short u16;
typedef __attribute__((ext_vector_type(8))) short short8;
typedef __attribute__((ext_vector_type(4))) float f32x4;

// Problem constants: B=2, T=2048, C=2048, H=16, HD=128
#define TSEQ 2048
#define NHEAD 16
#define HDIM 128

__device__ __forceinline__ u16 f2bf(float x) {
    unsigned u = __float_as_uint(x);
    return (u16)((u + 0x7fffu + ((u >> 16) & 1u)) >> 16);
}
__device__ __forceinline__ float b2f(u16 h) {
    return __uint_as_float(((unsigned)h) << 16);
}
__device__ __forceinline__ void async16(const void* g, void* l) {
    __builtin_amdgcn_global_load_lds((__attribute__((address_space(1))) void*)(void*)g,
                                     (__attribute__((address_space(3))) void*)l, 16, 0, 0);
}
__device__ __forceinline__ f32x4 zero4() {
    f32x4 z = {0.f, 0.f, 0.f, 0.f};
    return z;
}

// DPP cross-lane (16-lane group reductions), no LDS traffic
template <int CTRL>
__device__ __forceinline__ float dppf(float x) {
    return __int_as_float(__builtin_amdgcn_mov_dpp(__float_as_int(x), CTRL, 0xf, 0xf, true));
}
__device__ __forceinline__ float dpp_max16(float x) {
    x = fmaxf(x, dppf<0xB1>(x));   // quad_perm xor1
    x = fmaxf(x, dppf<0x4E>(x));   // quad_perm xor2
    x = fmaxf(x, dppf<0x141>(x));  // row_half_mirror (~xor4)
    x = fmaxf(x, dppf<0x140>(x));  // row_mirror (~xor8)
    return x;
}
__device__ __forceinline__ float dpp_sum16(float x) {
    x += dppf<0xB1>(x);
    x += dppf<0x4E>(x);
    x += dppf<0x141>(x);
    x += dppf<0x140>(x);
    return x;
}

// ---------------- cast x (f32 -> bf16), vectorized ----------------
__global__ void cast_bf16(const float4* __restrict__ in, ushort4* __restrict__ out, int n4) {
    int i = blockIdx.x * 256 + threadIdx.x;
    if (i < n4) {
        float4 v = in[i];
        ushort4 o;
        o.x = f2bf(v.x); o.y = f2bf(v.y); o.z = f2bf(v.z); o.w = f2bf(v.w);
        out[i] = o;
    }
}

// ---------------- transpose + cast: in f32 [K][N] -> out bf16 [N][K] ----------------
__global__ void transpose_cast(const float* __restrict__ in, u16* __restrict__ out, int K, int N) {
    __shared__ float tile[64][65];
    int n0 = blockIdx.x * 64, k0 = blockIdx.y * 64;
    int tx = threadIdx.x & 63, ty = threadIdx.x >> 6;
#pragma unroll
    for (int i = 0; i < 16; i++) {
        int r = ty + i * 4;
        tile[r][tx] = in[(size_t)(k0 + r) * N + n0 + tx];
    }
    __syncthreads();
#pragma unroll
    for (int i = 0; i < 16; i++) {
        int r = ty + i * 4;
        out[(size_t)(n0 + r) * K + k0 + tx] = f2bf(tile[tx][r]);
    }
}

// ================= shared schedule macros (T2 swizzle, counted vmcnt) ========
#define WAIT_DS()                                          \
    {                                                      \
        asm volatile("s_waitcnt lgkmcnt(0)" ::: "memory"); \
        __builtin_amdgcn_sched_barrier(0);                 \
    }
#define BAR() __builtin_amdgcn_s_barrier();
#define VBAR_(N)                                               \
    {                                                          \
        asm volatile("s_waitcnt vmcnt(" #N ")" ::: "memory");  \
        __builtin_amdgcn_s_barrier();                          \
    }
#define VBAR(N) VBAR_(N)

// stage one 128-row half-tile: 2 x global_load_lds per thread (16 KiB across 8 waves).
// LDS dest linear; global source pre-swizzled: slot = (lane&7) ^ (row&7)  (rule #21).
#define STAGE(GP, GROW0, LB, KT)                                                                 \
    {                                                                                            \
        const u16* g0__ = (GP) + (size_t)((GROW0) + wave * 16 + grow) * (size_t)K + (KT)*64 +    \
                          gslot * 8;                                                             \
        u16* l0__ = (LB) + wave * 1024;                                                          \
        async16(g0__, l0__);                                                                     \
        async16(g0__ + (size_t)8 * K, l0__ + 512);                                               \
    }

#define LDA4(BASE, MB)                                                              \
    {                                                                               \
        _Pragma("unroll") for (int mm = 0; mm < 4; ++mm) {                          \
            a[mm][0] = *(const short8*)((BASE) + aoff0 + ((MB) + mm) * 1024);       \
            a[mm][1] = *(const short8*)((BASE) + aoff1 + ((MB) + mm) * 1024);       \
        }                                                                           \
    }
#define LDB2(BASE, NB)                                                              \
    {                                                                               \
        _Pragma("unroll") for (int nn = 0; nn < 2; ++nn) {                          \
            b[(NB) + nn][0] = *(const short8*)((BASE) + boff0 + ((NB) + nn) * 1024);\
            b[(NB) + nn][1] = *(const short8*)((BASE) + boff1 + ((NB) + nn) * 1024);\
        }                                                                           \
    }
#define MFQ(MB, NB)                                                                                   \
    {                                                                                                 \
        _Pragma("unroll") for (int mm = 0; mm < 4; ++mm) _Pragma("unroll") for (int nn = 0; nn < 2;   \
                                                                                ++nn) {               \
            acc[(MB) + mm][(NB) + nn] = __builtin_amdgcn_mfma_f32_16x16x32_bf16(                      \
                a[mm][0], b[(NB) + nn][0], acc[(MB) + mm][(NB) + nn], 0, 0, 0);                       \
            acc[(MB) + mm][(NB) + nn] = __builtin_amdgcn_mfma_f32_16x16x32_bf16(                      \
                a[mm][1], b[(NB) + nn][1], acc[(MB) + mm][(NB) + nn], 0, 0, 0);                       \
        }                                                                                             \
    }
#define PRIO_MFQ(MB, NB)                \
    {                                   \
        __builtin_amdgcn_s_setprio(1);  \
        MFQ(MB, NB);                    \
        __builtin_amdgcn_s_setprio(0);  \
    }

// ---------------- 256x256 8-phase GEMM (QKV, fused RoPE + v-transpose epilogue) ----------------
// 8 waves = 2M x 4N, per-wave 128x64, BK=64. LDS 128 KiB dbuf. 1 block/CU.
// R5: schedule reverted to the VERIFIED R3 loop. NOTE for future edits: LDA4/LDB2 read
// patterns span BOTH 128-row halves of each buffer (wr=1 waves read rows 128-191 in the
// "first" A phase; wc=2,3 waves read B rows 128+ in the first B phase), so a buffer
// region is restageable only after ALL reads of that buffer (A: after LDA4(...,4);
// B: after LDB2(...,2)) have crossed a barrier. The R4 region-granular schedule
// violated this (staged A rows 64-127 before their ph3 read) -> absmax 0.52.
__global__ __launch_bounds__(512, 2) void gemm256(
    const u16* __restrict__ A, const u16* __restrict__ Bt, const float* __restrict__ bias,
    u16* __restrict__ qb, u16* __restrict__ kb, u16* __restrict__ vT,
    const float* __restrict__ cosp, const float* __restrict__ sinp,
    int M, int N, int K) {
    extern __shared__ u16 sm[];
    u16* const smA0 = sm;             // 256x64
    u16* const smB0 = sm + 16384;     // 256x64
    u16* const smA1 = sm + 32768;
    u16* const smB1 = sm + 49152;

    const int tid = threadIdx.x;
    const int wave = tid >> 6, lane = tid & 63;
    const int low = lane & 15, quad = lane >> 4;
    const int wr = wave >> 2, wc = wave & 3;
    const int m0 = blockIdx.y * 256, n0 = blockIdx.x * 256;
    const int NT = K >> 6;  // 64-wide K tiles

    const int grow = lane >> 3;            // row within 8-row chunk
    const int gslot = (lane & 7) ^ grow;   // pre-swizzled 16B slot

    const int swz = low & 7;
    const int arow = (wr * 128 + low) * 64;
    const int brow = (wc * 64 + low) * 64;
    const int aoff0 = arow + ((0 + quad) ^ swz) * 8;
    const int aoff1 = arow + ((4 + quad) ^ swz) * 8;
    const int boff0 = brow + ((0 + quad) ^ swz) * 8;
    const int boff1 = brow + ((4 + quad) ^ swz) * 8;

    f32x4 acc[8][4];
#pragma unroll
    for (int i = 0; i < 8; i++)
#pragma unroll
        for (int j = 0; j < 4; j++) acc[i][j] = zero4();
    short8 a[4][2], b[4][2];

    // ---- prologue: tile0 -> buf0, tile1 -> buf1 ----
    STAGE(A, m0, smA0, 0);
    STAGE(A, m0 + 128, smA0 + 8192, 0);
    STAGE(Bt, n0, smB0, 0);
    STAGE(Bt, n0 + 128, smB0 + 8192, 0);
    STAGE(A, m0, smA1, 1);
    STAGE(A, m0 + 128, smA1 + 8192, 1);
    STAGE(Bt, n0, smB1, 1);
    STAGE(Bt, n0 + 128, smB1 + 8192, 1);
    VBAR(8);  // tile0 landed; tile1 (8 loads) in flight

    const int NI = (NT >> 1) - 1;
#pragma unroll 1
    for (int it = 0; it < NI; ++it) {
        const int e = it * 2;
        // ---- K-tile e (buf0) ----
        LDA4(smA0, 0);
        LDB2(smB0, 0);
        LDB2(smB0, 2);
        PRIO_MFQ(0, 0);
        PRIO_MFQ(0, 2);
        LDA4(smA0, 4);
        WAIT_DS();
        BAR();  // all buf0 reads complete chip-wide -> buf0 restage may begin
        PRIO_MFQ(4, 2);
        STAGE(A, m0, smA0, e + 2);
        STAGE(Bt, n0, smB0, e + 2);
        PRIO_MFQ(4, 0);
        VBAR(4);  // drain tile e+1 (prev ph8's 8 loads); e+2's 4 stay in flight
        // ---- K-tile e+1 (buf1) ----
        LDA4(smA1, 0);
        LDB2(smB1, 0);
        LDB2(smB1, 2);
        STAGE(A, m0 + 128, smA0 + 8192, e + 2);
        STAGE(Bt, n0 + 128, smB0 + 8192, e + 2);
        PRIO_MFQ(0, 0);
        PRIO_MFQ(0, 2);
        LDA4(smA1, 4);
        WAIT_DS();
        BAR();  // all buf1 reads complete -> buf1 restage may begin
        PRIO_MFQ(4, 2);
        STAGE(A, m0, smA1, e + 3);
        STAGE(A, m0 + 128, smA1 + 8192, e + 3);
        STAGE(Bt, n0, smB1, e + 3);
        STAGE(Bt, n0 + 128, smB1 + 8192, e + 3);
        PRIO_MFQ(4, 0);
        VBAR(8);  // drain tile e+2 (4+4); e+3's 8 stay in flight
    }
    // ---- peeled last pair (K-tiles NT-2, NT-1): no stages ----
    LDA4(smA0, 0);
    LDB2(smB0, 0);
    LDB2(smB0, 2);
    PRIO_MFQ(0, 0);
    PRIO_MFQ(0, 2);
    LDA4(smA0, 4);
    PRIO_MFQ(4, 2);
    PRIO_MFQ(4, 0);
    VBAR(0);  // drain tile NT-1's 8 before reading buf1
    LDA4(smA1, 0);
    LDB2(smB1, 0);
    LDB2(smB1, 2);
    PRIO_MFQ(0, 0);
    PRIO_MFQ(0, 2);
    LDA4(smA1, 4);
    PRIO_MFQ(4, 2);
    PRIO_MFQ(4, 0);

    __syncthreads();  // drain everything before LDS reuse in epilogue

    // ---- epilogue: n-tile spans 2 heads of one of {q,k,v} ----
    const int which = n0 >> 11;           // 0=q 1=k 2=v
    const int h0 = (n0 & 2047) >> 7;      // first head in tile (even)
    const int bb = m0 >> 11, t0 = m0 & 2047;
    float bvv[4];
#pragma unroll
    for (int nn = 0; nn < 4; ++nn) bvv[nn] = bias[n0 + wc * 64 + nn * 16 + low];

    if (which < 2) {
        // q/k: [bh][t][d] with fused RoPE. epi tile [256][136] bf16 per head-half.
        u16* dstb = (which == 0 ? qb : kb);
        u16* epi = sm;
#pragma unroll
        for (int hh = 0; hh < 2; ++hh) {
            if ((wc >> 1) == hh) {
#pragma unroll
                for (int mm = 0; mm < 8; ++mm)
#pragma unroll
                    for (int nn = 0; nn < 4; ++nn)
#pragma unroll
                        for (int rr = 0; rr < 4; ++rr)
                            epi[(wr * 128 + mm * 16 + quad * 4 + rr) * 136 +
                                (wc & 1) * 64 + nn * 16 + low] = f2bf(acc[mm][nn][rr] + bvv[nn]);
            }
            __syncthreads();
            {
                const int row = tid >> 1, dh = (tid & 1) * 64;
                const int t = t0 + row;
                u16* dr = dstb + (((size_t)(bb * NHEAD + h0 + hh)) * TSEQ + t) * HDIM + dh;
                u16 vals[64];
#pragma unroll
                for (int qq = 0; qq < 8; ++qq)
                    *(short8*)(vals + qq * 8) = *(const short8*)(epi + row * 136 + dh + qq * 8);
                float csv[32], snv[32];
#pragma unroll
                for (int qq = 0; qq < 8; ++qq) {
                    *(float4*)(csv + qq * 4) =
                        *(const float4*)(cosp + (size_t)t * 64 + (dh >> 1) + qq * 4);
                    *(float4*)(snv + qq * 4) =
                        *(const float4*)(sinp + (size_t)t * 64 + (dh >> 1) + qq * 4);
                }
                u16 ov[64];
#pragma unroll
                for (int pp = 0; pp < 32; ++pp) {
                    float x0 = b2f(vals[2 * pp]), x1 = b2f(vals[2 * pp + 1]);
                    ov[2 * pp] = f2bf(x0 * csv[pp] - x1 * snv[pp]);
                    ov[2 * pp + 1] = f2bf(x0 * snv[pp] + x1 * csv[pp]);
                }
#pragma unroll
                for (int qq = 0; qq < 8; ++qq)
                    *(short8*)(dr + qq * 8) = *(const short8*)(ov + qq * 8);
            }
            __syncthreads();
        }
    } else {
        // v: write transposed [bh][d][t]. epi tile [128 d][264 (256 t + pad)] per head-half.
        u16* epi = sm;
#pragma unroll
        for (int hh = 0; hh < 2; ++hh) {
            if ((wc >> 1) == hh) {
#pragma unroll
                for (int mm = 0; mm < 8; ++mm)
#pragma unroll
                    for (int nn = 0; nn < 4; ++nn)
#pragma unroll
                        for (int rr = 0; rr < 4; ++rr)
                            epi[((wc & 1) * 64 + nn * 16 + low) * 264 +
                                wr * 128 + mm * 16 + quad * 4 + rr] = f2bf(acc[mm][nn][rr] + bvv[nn]);
            }
            __syncthreads();
            {
                const int dd = tid >> 2, tc = (tid & 3) * 64;
                u16* dr = vT + ((size_t)(bb * NHEAD + h0 + hh) * HDIM + dd) * TSEQ + t0 + tc;
#pragma unroll
                for (int qq = 0; qq < 8; ++qq)
                    *(short8*)(dr + qq * 8) = *(const short8*)(epi + dd * 264 + tc + qq * 8);
            }
            __syncthreads();
        }
    }
}

// ---------------- proj GEMM: out(f32) = y(bf16) @ WpT(bf16) + bias ----------------
// 128x256 tile, BK=64, 8 waves 2M x 4N (64x64/wave). Grid 32x8 = 256 blocks = 1/CU exact.
#define PMFQ(NB)                                                                                      \
    {                                                                                                 \
        _Pragma("unroll") for (int mm = 0; mm < 4; ++mm) _Pragma("unroll") for (int nn = 0; nn < 2;   \
                                                                                ++nn) {               \
            acc[mm][(NB) + nn] = __builtin_amdgcn_mfma_f32_16x16x32_bf16(                             \
                a[mm][0], b[(NB) + nn][0], acc[mm][(NB) + nn], 0, 0, 0);                              \
            acc[mm][(NB) + nn] = __builtin_amdgcn_mfma_f32_16x16x32_bf16(                             \
                a[mm][1], b[(NB) + nn][1], acc[mm][(NB) + nn], 0, 0, 0);                              \
        }                                                                                             \
    }
#define PPRIO_MFQ(NB)                   \
    {                                   \
        __builtin_amdgcn_s_setprio(1);  \
        PMFQ(NB);                       \
        __builtin_amdgcn_s_setprio(0);  \
    }

__global__ __launch_bounds__(512, 2) void pgemm(
    const u16* __restrict__ A, const u16* __restrict__ Bt, const float* __restrict__ bias,
    float* __restrict__ outf, int M, int N, int K) {
    extern __shared__ u16 sm[];
    u16* const smA0 = sm;             // 128x64
    u16* const smB0 = sm + 8192;      // 256x64
    u16* const smA1 = sm + 24576;
    u16* const smB1 = sm + 32768;     // total 49152 u16 = 96 KiB

    const int tid = threadIdx.x;
    const int wave = tid >> 6, lane = tid & 63;
    const int low = lane & 15, quad = lane >> 4;
    const int wr = wave >> 2, wc = wave & 3;
    const int m0 = blockIdx.y * 128, n0 = blockIdx.x * 256;
    const int NT = K >> 6;

    const int grow = lane >> 3;
    const int gslot = (lane & 7) ^ grow;

    const int swz = low & 7;
    const int arow = (wr * 64 + low) * 64;
    const int brow = (wc * 64 + low) * 64;
    const int aoff0 = arow + ((0 + quad) ^ swz) * 8;
    const int aoff1 = arow + ((4 + quad) ^ swz) * 8;
    const int boff0 = brow + ((0 + quad) ^ swz) * 8;
    const int boff1 = brow + ((4 + quad) ^ swz) * 8;

    f32x4 acc[4][4];
#pragma unroll
    for (int i = 0; i < 4; i++)
#pragma unroll
        for (int j = 0; j < 4; j++) acc[i][j] = zero4();
    short8 a[4][2], b[4][2];

    // ---- prologue: tile0 -> buf0 (6 loads/thread), tile1 -> buf1 (6) ----
    STAGE(A, m0, smA0, 0);
    STAGE(Bt, n0, smB0, 0);
    STAGE(Bt, n0 + 128, smB0 + 8192, 0);
    STAGE(A, m0, smA1, 1);
    STAGE(Bt, n0, smB1, 1);
    STAGE(Bt, n0 + 128, smB1 + 8192, 1);
    VBAR(6);  // tile0 landed; tile1 (6) in flight

    const int NI = (NT >> 1) - 1;
#pragma unroll 1
    for (int it = 0; it < NI; ++it) {
        const int e = it * 2;
        // ---- K-tile e (buf0) ----
        LDA4(smA0, 0);
        LDB2(smB0, 0);
        LDB2(smB0, 2);
        PPRIO_MFQ(0);
        WAIT_DS();
        BAR();  // all buf0 reads retired -> restage buf0
        STAGE(A, m0, smA0, e + 2);
        STAGE(Bt, n0, smB0, e + 2);
        STAGE(Bt, n0 + 128, smB0 + 8192, e + 2);
        PPRIO_MFQ(2);
        VBAR(6);  // drain tile e+1 (6, staged last iter); e+2's 6 in flight
        // ---- K-tile e+1 (buf1) ----
        LDA4(smA1, 0);
        LDB2(smB1, 0);
        LDB2(smB1, 2);
        PPRIO_MFQ(0);
        WAIT_DS();
        BAR();
        STAGE(A, m0, smA1, e + 3);
        STAGE(Bt, n0, smB1, e + 3);
        STAGE(Bt, n0 + 128, smB1 + 8192, e + 3);
        PPRIO_MFQ(2);
        VBAR(6);  // drain tile e+2; e+3's 6 in flight
    }
    // ---- peeled last pair: no stages ----
    LDA4(smA0, 0);
    LDB2(smB0, 0);
    LDB2(smB0, 2);
    PPRIO_MFQ(0);
    PPRIO_MFQ(2);
    VBAR(0);  // drain tile NT-1 before reading buf1
    LDA4(smA1, 0);
    LDB2(smB1, 0);
    LDB2(smB1, 2);
    PPRIO_MFQ(0);
    PPRIO_MFQ(2);

    // ---- epilogue: direct coalesced f32 stores ----
    float bvv[4];
#pragma unroll
    for (int nn = 0; nn < 4; ++nn) bvv[nn] = bias[n0 + wc * 64 + nn * 16 + low];
#pragma unroll
    for (int mm = 0; mm < 4; ++mm) {
        const int rbase = m0 + wr * 64 + mm * 16 + quad * 4;
#pragma unroll
        for (int nn = 0; nn < 4; ++nn) {
            const int col = n0 + wc * 64 + nn * 16 + low;
#pragma unroll
            for (int r = 0; r < 4; ++r)
                outf[(size_t)(rbase + r) * N + col] = acc[mm][nn][r] + bvv[nn];
        }
    }
}

// ---------------- Flash attention: double-buffered K/V, 64-key tiles, DPP softmax ----------------
// Prefetch tile kt+1 during compute of kt (1 barrier/tile, stage latency hidden under
// ~700cy of MFMA+softmax); causal mask applied only on the diagonal tile (block-uniform).
// Hazard ledger: stage at iter kt targets buf[(kt+1)&1], whose last reads (iter kt-1)
// retired before this iter's vmcnt(0)+barrier; vmcnt(0)+barrier at iter top proves tile
// kt fully landed for all waves before any read.
#define STAGE_KV(KT, SEL)                                                                   \
    {                                                                                       \
        const int kv0s = (KT) * 64;                                                         \
        _Pragma("unroll") for (int j = 0; j < 4; j++) {                                     \
            const int row = j * 16 + krow;                                                  \
            const int gc = kchunk ^ (row & 7);                                              \
            async16(Kb + (size_t)(kv0s + row) * HDIM + gc * 8,                              \
                    Ksb + (SEL)*8192 + row * 128 + kchunk * 8);                             \
        }                                                                                   \
        _Pragma("unroll") for (int j = 0; j < 4; j++) {                                     \
            const int d = j * 32 + vrow;                                                    \
            const int gc = vchunk ^ (d & 7);                                                \
            async16(Vb + (size_t)d * TSEQ + kv0s + gc * 8,                                  \
                    Vsb + (SEL)*8192 + d * 64 + vchunk * 8);                                \
        }                                                                                   \
    }

__global__ __launch_bounds__(256) void flash_attn(const u16* __restrict__ qb, const u16* __restrict__ kb,
                                                  const u16* __restrict__ vT, u16* __restrict__ y) {
    extern __shared__ u16 fsm[];
    u16* const Ksb = fsm;               // [2][64*128] keys, xor-swizzled by (key&7)
    u16* const Vsb = fsm + 16384;       // [2][128*64] values, xor-swizzled by (d&7)
    u16* const Psb = fsm + 32768;       // [4][16*72] per-wave P
    const int tid = threadIdx.x;
    const int wave = tid >> 6, lane = tid & 63;
    const int low = lane & 15, quad = lane >> 4;
    const int bh = blockIdx.x;
    const int qt = 31 - blockIdx.y;          // longest blocks first
    const int q0 = qt * 64 + wave * 16;
    const float scale2 = 0.08838834764831845f * 1.44269504088896f;  // 1/sqrt(128) * log2(e)

    const u16* Qp = qb + ((size_t)bh * TSEQ + q0) * HDIM;
    short8 qf[4];
#pragma unroll
    for (int c = 0; c < 4; c++) qf[c] = *(const short8*)(Qp + (size_t)low * HDIM + c * 32 + quad * 8);

    f32x4 o[8];
#pragma unroll
    for (int d = 0; d < 8; d++) o[d] = zero4();
    float m_i[4], l_i[4];
#pragma unroll
    for (int r = 0; r < 4; r++) { m_i[r] = -1e30f; l_i[r] = 0.f; }

    const u16* Kb = kb + (size_t)bh * TSEQ * HDIM;
    const u16* Vb = vT + (size_t)bh * HDIM * TSEQ;
    u16* Pw = Psb + wave * 1152;
    const int ntiles = qt + 1;

    const int krow = tid >> 4, kchunk = tid & 15;   // K: 16 rows x 16 chunks per issue
    const int vrow = tid >> 3, vchunk = tid & 7;    // V: 32 rows x 8 chunks per issue

    STAGE_KV(0, 0);
    for (int kt = 0; kt < ntiles; ++kt) {
        const int kv0 = kt * 64;
        VBAR(0);  // tile kt landed (all waves); prior reads of the other buffer done
        if (kt + 1 < ntiles) STAGE_KV(kt + 1, (kt + 1) & 1);
        const u16* Kc = Ksb + (kt & 1) * 8192;
        const u16* Vc = Vsb + (kt & 1) * 8192;

        // ---- QK^T: S[16q x 64k] ----
        f32x4 s[4];
#pragma unroll
        for (int h = 0; h < 4; h++) s[h] = zero4();
        __builtin_amdgcn_s_setprio(1);
#pragma unroll
        for (int h = 0; h < 4; h++) {
            const int row = h * 16 + low;
#pragma unroll
            for (int c = 0; c < 4; c++) {
                const int cc = c * 4 + quad;
                short8 kf = *(const short8*)(Kc + row * 128 + (cc ^ (row & 7)) * 8);
                s[h] = __builtin_amdgcn_mfma_f32_16x16x32_bf16(qf[c], kf, s[h], 0, 0, 0);
            }
        }
        __builtin_amdgcn_s_setprio(0);

        // ---- online softmax (exp2 domain), DPP reductions; mask only diagonal tile ----
        float alpha[4];
#pragma unroll
        for (int r = 0; r < 4; r++) {
            const int qg = q0 + quad * 4 + r;
            float sv[4];
#pragma unroll
            for (int h = 0; h < 4; h++) sv[h] = s[h][r] * scale2;
            if (kt == qt) {  // block-uniform branch: only diagonal tile masks
#pragma unroll
                for (int h = 0; h < 4; h++)
                    if (kv0 + h * 16 + low > qg) sv[h] = -1e30f;
            }
            float mx = fmaxf(fmaxf(sv[0], sv[1]), fmaxf(sv[2], sv[3]));
            mx = dpp_max16(mx);
            float mnew = fmaxf(m_i[r], mx);
            alpha[r] = exp2f(m_i[r] - mnew);
            m_i[r] = mnew;
            float p0 = exp2f(sv[0] - mnew);
            float p1 = exp2f(sv[1] - mnew);
            float p2 = exp2f(sv[2] - mnew);
            float p3 = exp2f(sv[3] - mnew);
            float rs = (p0 + p1) + (p2 + p3);
            rs = dpp_sum16(rs);
            l_i[r] = l_i[r] * alpha[r] + rs;
            const int prow = (quad * 4 + r) * 72;
            Pw[prow + low] = f2bf(p0);
            Pw[prow + 16 + low] = f2bf(p1);
            Pw[prow + 32 + low] = f2bf(p2);
            Pw[prow + 48 + low] = f2bf(p3);
        }
        __threadfence_block();

#pragma unroll
        for (int d = 0; d < 8; ++d)
#pragma unroll
            for (int r = 0; r < 4; r++) o[d][r] *= alpha[r];

        // ---- PV ----
        __builtin_amdgcn_s_setprio(1);
#pragma unroll
        for (int kc = 0; kc < 2; kc++) {
            short8 pf = *(const short8*)(Pw + low * 72 + kc * 32 + quad * 8);
#pragma unroll
            for (int dd = 0; dd < 8; ++dd) {
                const int vr = dd * 16 + low;
                const int cc = kc * 4 + quad;
                short8 vf = *(const short8*)(Vc + vr * 64 + (cc ^ (vr & 7)) * 8);
                o[dd] = __builtin_amdgcn_mfma_f32_16x16x32_bf16(pf, vf, o[dd], 0, 0, 0);
            }
        }
        __builtin_amdgcn_s_setprio(0);
    }

    const int b = bh >> 4, h = bh & 15;
#pragma unroll
    for (int r = 0; r < 4; r++) {
        float inv = 1.0f / l_i[r];
        size_t row = (size_t)(b * TSEQ + q0 + quad * 4 + r);
        u16* yp = y + row * 2048 + h * HDIM;
#pragma unroll
        for (int d = 0; d < 8; ++d) yp[d * 16 + low] = f2bf(o[d][r] * inv);
    }
}

extern "C" void kernel_launch(void* const* d_in, const int* in_sizes, int n_in,
                              void* d_out, int out_size, void* d_ws, size_t ws_size,
                              hipStream_t stream) {
    const float* x = (const float*)d_in[0];
    const float* Wa = (const float*)d_in[1];
    const float* ba = (const float*)d_in[2];
    const float* Wp = (const float*)d_in[3];
    const float* bp = (const float*)d_in[4];
    const float* cs = (const float*)d_in[5];
    const float* sn = (const float*)d_in[6];
    float* out = (float*)d_out;

    u16* xb = (u16*)d_ws;             // x bf16; reused later as y
    u16* Wab = xb + 8388608;          // W_attn^T bf16 [6144][2048]
    u16* Wpb = Wab + 12582912;        // W_proj^T bf16 [2048][2048]
    u16* qb = Wpb + 4194304;          // [bh][t][d]
    u16* kb = qb + 8388608;           // [bh][t][d]
    u16* vT = kb + 8388608;           // [bh][d][t]
    u16* y = xb;

    static bool attr_set = false;
    if (!attr_set) {
        hipFuncSetAttribute(reinterpret_cast<const void*>(gemm256),
                            hipFuncAttributeMaxDynamicSharedMemorySize, 131072);
        hipFuncSetAttribute(reinterpret_cast<const void*>(pgemm),
                            hipFuncAttributeMaxDynamicSharedMemorySize, 98304);
        hipFuncSetAttribute(reinterpret_cast<const void*>(flash_attn),
                            hipFuncAttributeMaxDynamicSharedMemorySize, 74752);
        attr_set = true;
    }

    cast_bf16<<<8192, 256, 0, stream>>>((const float4*)x, (ushort4*)xb, 2097152);
    transpose_cast<<<dim3(96, 32), 256, 0, stream>>>(Wa, Wab, 2048, 6144);
    transpose_cast<<<dim3(32, 32), 256, 0, stream>>>(Wp, Wpb, 2048, 2048);
    gemm256<<<dim3(24, 16), 512, 131072, stream>>>(xb, Wab, ba, qb, kb, vT, cs, sn, 4096, 6144, 2048);
    flash_attn<<<dim3(32, 32), 256, 74752, stream>>>(qb, kb, vT, y);
    pgemm<<<dim3(8, 32), 512, 98304, stream>>>(y, Wpb, bp, out, 4096, 2048, 2048);
}

// Round 9
// 390.284 us; speedup vs baseline: 1.0236x; 1.0236x over previous
//
#include <hip/hip_runtime.h>

typedef unsigned short u16;
typedef __attribute__((ext_vector_type(8))) short short8;
typedef __attribute__((ext_vector_type(4))) float f32x4;

// Problem constants: B=2, T=2048, C=2048, H=16, HD=128
#define TSEQ 2048
#define NHEAD 16
#define HDIM 128

__device__ __forceinline__ u16 f2bf(float x) {
    unsigned u = __float_as_uint(x);
    return (u16)((u + 0x7fffu + ((u >> 16) & 1u)) >> 16);
}
__device__ __forceinline__ float b2f(u16 h) {
    return __uint_as_float(((unsigned)h) << 16);
}
__device__ __forceinline__ void async16(const void* g, void* l) {
    __builtin_amdgcn_global_load_lds((__attribute__((address_space(1))) void*)(void*)g,
                                     (__attribute__((address_space(3))) void*)l, 16, 0, 0);
}
__device__ __forceinline__ f32x4 zero4() {
    f32x4 z = {0.f, 0.f, 0.f, 0.f};
    return z;
}

// DPP cross-lane (16-lane group reductions), no LDS traffic
template <int CTRL>
__device__ __forceinline__ float dppf(float x) {
    return __int_as_float(__builtin_amdgcn_mov_dpp(__float_as_int(x), CTRL, 0xf, 0xf, true));
}
__device__ __forceinline__ float dpp_max16(float x) {
    x = fmaxf(x, dppf<0xB1>(x));   // quad_perm xor1
    x = fmaxf(x, dppf<0x4E>(x));   // quad_perm xor2
    x = fmaxf(x, dppf<0x141>(x));  // row_half_mirror (~xor4)
    x = fmaxf(x, dppf<0x140>(x));  // row_mirror (~xor8)
    return x;
}
__device__ __forceinline__ float dpp_sum16(float x) {
    x += dppf<0xB1>(x);
    x += dppf<0x4E>(x);
    x += dppf<0x141>(x);
    x += dppf<0x140>(x);
    return x;
}

// ---------------- fused prep: cast x (f32->bf16) + transpose_cast Wa + Wp ----------------
// blocks [0,8192): cast; [8192,11264): Wa transpose (96x32); [11264,12288): Wp (32x32).
__global__ __launch_bounds__(256) void prep(
    const float* __restrict__ x, u16* __restrict__ xb,
    const float* __restrict__ Wa, u16* __restrict__ Wab,
    const float* __restrict__ Wp, u16* __restrict__ Wpb) {
    __shared__ float tile[64][65];
    const int bx = blockIdx.x;
    const int tid = threadIdx.x;
    if (bx < 8192) {
        int i = bx * 256 + tid;
        float4 v = ((const float4*)x)[i];
        ushort4 o;
        o.x = f2bf(v.x); o.y = f2bf(v.y); o.z = f2bf(v.z); o.w = f2bf(v.w);
        ((ushort4*)xb)[i] = o;
        return;
    }
    const float* in;
    u16* out;
    int K, N, n0, k0;
    if (bx < 11264) {
        const int bid = bx - 8192;
        in = Wa; out = Wab; K = 2048; N = 6144;
        n0 = (bid % 96) * 64; k0 = (bid / 96) * 64;
    } else {
        const int bid = bx - 11264;
        in = Wp; out = Wpb; K = 2048; N = 2048;
        n0 = (bid % 32) * 64; k0 = (bid / 32) * 64;
    }
    const int tx = tid & 63, ty = tid >> 6;
#pragma unroll
    for (int i = 0; i < 16; i++) {
        int r = ty + i * 4;
        tile[r][tx] = in[(size_t)(k0 + r) * N + n0 + tx];
    }
    __syncthreads();
#pragma unroll
    for (int i = 0; i < 16; i++) {
        int r = ty + i * 4;
        out[(size_t)(n0 + r) * K + k0 + tx] = f2bf(tile[tx][r]);
    }
}

// ================= shared schedule macros (T2 swizzle, counted vmcnt) ========
#define WAIT_DS()                                          \
    {                                                      \
        asm volatile("s_waitcnt lgkmcnt(0)" ::: "memory"); \
        __builtin_amdgcn_sched_barrier(0);                 \
    }
#define BAR() __builtin_amdgcn_s_barrier();
#define VBAR_(N)                                               \
    {                                                          \
        asm volatile("s_waitcnt vmcnt(" #N ")" ::: "memory");  \
        __builtin_amdgcn_s_barrier();                          \
    }
#define VBAR(N) VBAR_(N)

// stage one 128-row half-tile: 2 x global_load_lds per thread (16 KiB across 8 waves).
// LDS dest linear; global source pre-swizzled: slot = (lane&7) ^ (row&7)  (rule #21).
// NOTE (m104, R6 lesson): global_load_lds writes LDS at wave-uniform base + lane*16B;
// any staging pattern must make the intended per-lane LDS offset EQUAL base+lane*16.
#define STAGE(GP, GROW0, LB, KT)                                                                 \
    {                                                                                            \
        const u16* g0__ = (GP) + (size_t)((GROW0) + wave * 16 + grow) * (size_t)K + (KT)*64 +    \
                          gslot * 8;                                                             \
        u16* l0__ = (LB) + wave * 1024;                                                          \
        async16(g0__, l0__);                                                                     \
        async16(g0__ + (size_t)8 * K, l0__ + 512);                                               \
    }

#define LDA4(BASE, MB)                                                              \
    {                                                                               \
        _Pragma("unroll") for (int mm = 0; mm < 4; ++mm) {                          \
            a[mm][0] = *(const short8*)((BASE) + aoff0 + ((MB) + mm) * 1024);       \
            a[mm][1] = *(const short8*)((BASE) + aoff1 + ((MB) + mm) * 1024);       \
        }                                                                           \
    }
#define LDB2(BASE, NB)                                                              \
    {                                                                               \
        _Pragma("unroll") for (int nn = 0; nn < 2; ++nn) {                          \
            b[(NB) + nn][0] = *(const short8*)((BASE) + boff0 + ((NB) + nn) * 1024);\
            b[(NB) + nn][1] = *(const short8*)((BASE) + boff1 + ((NB) + nn) * 1024);\
        }                                                                           \
    }
#define MFQ(MB, NB)                                                                                   \
    {                                                                                                 \
        _Pragma("unroll") for (int mm = 0; mm < 4; ++mm) _Pragma("unroll") for (int nn = 0; nn < 2;   \
                                                                                ++nn) {               \
            acc[(MB) + mm][(NB) + nn] = __builtin_amdgcn_mfma_f32_16x16x32_bf16(                      \
                a[mm][0], b[(NB) + nn][0], acc[(MB) + mm][(NB) + nn], 0, 0, 0);                       \
            acc[(MB) + mm][(NB) + nn] = __builtin_amdgcn_mfma_f32_16x16x32_bf16(                      \
                a[mm][1], b[(NB) + nn][1], acc[(MB) + mm][(NB) + nn], 0, 0, 0);                       \
        }                                                                                             \
    }
#define PRIO_MFQ(MB, NB)                \
    {                                   \
        __builtin_amdgcn_s_setprio(1);  \
        MFQ(MB, NB);                    \
        __builtin_amdgcn_s_setprio(0);  \
    }

// ---------------- 256x256 8-phase GEMM (QKV, fused RoPE + v-transpose epilogue) ----------------
// 8 waves = 2M x 4N, per-wave 128x64, BK=64. LDS 128 KiB dbuf. 1 block/CU.
// VERIFIED R3 schedule. NOTE: LDA4/LDB2 read patterns span BOTH 128-row halves of each
// buffer, so a buffer region is restageable only after ALL reads of that buffer have
// crossed a barrier (R4's region-granular schedule violated this -> absmax 0.52).
__global__ __launch_bounds__(512, 2) void gemm256(
    const u16* __restrict__ A, const u16* __restrict__ Bt, const float* __restrict__ bias,
    u16* __restrict__ qb, u16* __restrict__ kb, u16* __restrict__ vT,
    const float* __restrict__ cosp, const float* __restrict__ sinp,
    int M, int N, int K) {
    extern __shared__ u16 sm[];
    u16* const smA0 = sm;             // 256x64
    u16* const smB0 = sm + 16384;     // 256x64
    u16* const smA1 = sm + 32768;
    u16* const smB1 = sm + 49152;

    const int tid = threadIdx.x;
    const int wave = tid >> 6, lane = tid & 63;
    const int low = lane & 15, quad = lane >> 4;
    const int wr = wave >> 2, wc = wave & 3;
    const int m0 = blockIdx.y * 256, n0 = blockIdx.x * 256;
    const int NT = K >> 6;  // 64-wide K tiles

    const int grow = lane >> 3;            // row within 8-row chunk
    const int gslot = (lane & 7) ^ grow;   // pre-swizzled 16B slot

    const int swz = low & 7;
    const int arow = (wr * 128 + low) * 64;
    const int brow = (wc * 64 + low) * 64;
    const int aoff0 = arow + ((0 + quad) ^ swz) * 8;
    const int aoff1 = arow + ((4 + quad) ^ swz) * 8;
    const int boff0 = brow + ((0 + quad) ^ swz) * 8;
    const int boff1 = brow + ((4 + quad) ^ swz) * 8;

    f32x4 acc[8][4];
#pragma unroll
    for (int i = 0; i < 8; i++)
#pragma unroll
        for (int j = 0; j < 4; j++) acc[i][j] = zero4();
    short8 a[4][2], b[4][2];

    // ---- prologue: tile0 -> buf0, tile1 -> buf1 ----
    STAGE(A, m0, smA0, 0);
    STAGE(A, m0 + 128, smA0 + 8192, 0);
    STAGE(Bt, n0, smB0, 0);
    STAGE(Bt, n0 + 128, smB0 + 8192, 0);
    STAGE(A, m0, smA1, 1);
    STAGE(A, m0 + 128, smA1 + 8192, 1);
    STAGE(Bt, n0, smB1, 1);
    STAGE(Bt, n0 + 128, smB1 + 8192, 1);
    VBAR(8);  // tile0 landed; tile1 (8 loads) in flight

    const int NI = (NT >> 1) - 1;
#pragma unroll 1
    for (int it = 0; it < NI; ++it) {
        const int e = it * 2;
        // ---- K-tile e (buf0) ----
        LDA4(smA0, 0);
        LDB2(smB0, 0);
        LDB2(smB0, 2);
        PRIO_MFQ(0, 0);
        PRIO_MFQ(0, 2);
        LDA4(smA0, 4);
        WAIT_DS();
        BAR();  // all buf0 reads complete chip-wide -> buf0 restage may begin
        PRIO_MFQ(4, 2);
        STAGE(A, m0, smA0, e + 2);
        STAGE(Bt, n0, smB0, e + 2);
        PRIO_MFQ(4, 0);
        VBAR(4);  // drain tile e+1 (prev ph8's 8 loads); e+2's 4 stay in flight
        // ---- K-tile e+1 (buf1) ----
        LDA4(smA1, 0);
        LDB2(smB1, 0);
        LDB2(smB1, 2);
        STAGE(A, m0 + 128, smA0 + 8192, e + 2);
        STAGE(Bt, n0 + 128, smB0 + 8192, e + 2);
        PRIO_MFQ(0, 0);
        PRIO_MFQ(0, 2);
        LDA4(smA1, 4);
        WAIT_DS();
        BAR();  // all buf1 reads complete -> buf1 restage may begin
        PRIO_MFQ(4, 2);
        STAGE(A, m0, smA1, e + 3);
        STAGE(A, m0 + 128, smA1 + 8192, e + 3);
        STAGE(Bt, n0, smB1, e + 3);
        STAGE(Bt, n0 + 128, smB1 + 8192, e + 3);
        PRIO_MFQ(4, 0);
        VBAR(8);  // drain tile e+2 (4+4); e+3's 8 stay in flight
    }
    // ---- peeled last pair (K-tiles NT-2, NT-1): no stages ----
    LDA4(smA0, 0);
    LDB2(smB0, 0);
    LDB2(smB0, 2);
    PRIO_MFQ(0, 0);
    PRIO_MFQ(0, 2);
    LDA4(smA0, 4);
    PRIO_MFQ(4, 2);
    PRIO_MFQ(4, 0);
    VBAR(0);  // drain tile NT-1's 8 before reading buf1
    LDA4(smA1, 0);
    LDB2(smB1, 0);
    LDB2(smB1, 2);
    PRIO_MFQ(0, 0);
    PRIO_MFQ(0, 2);
    LDA4(smA1, 4);
    PRIO_MFQ(4, 2);
    PRIO_MFQ(4, 0);

    __syncthreads();  // drain everything before LDS reuse in epilogue

    // ---- epilogue: n-tile spans 2 heads of one of {q,k,v} ----
    const int which = n0 >> 11;           // 0=q 1=k 2=v
    const int h0 = (n0 & 2047) >> 7;      // first head in tile (even)
    const int bb = m0 >> 11, t0 = m0 & 2047;
    float bvv[4];
#pragma unroll
    for (int nn = 0; nn < 4; ++nn) bvv[nn] = bias[n0 + wc * 64 + nn * 16 + low];

    if (which < 2) {
        // q/k: [bh][t][d] with fused RoPE. epi tile [256][136] bf16 per head-half.
        u16* dstb = (which == 0 ? qb : kb);
        u16* epi = sm;
#pragma unroll
        for (int hh = 0; hh < 2; ++hh) {
            if ((wc >> 1) == hh) {
#pragma unroll
                for (int mm = 0; mm < 8; ++mm)
#pragma unroll
                    for (int nn = 0; nn < 4; ++nn)
#pragma unroll
                        for (int rr = 0; rr < 4; ++rr)
                            epi[(wr * 128 + mm * 16 + quad * 4 + rr) * 136 +
                                (wc & 1) * 64 + nn * 16 + low] = f2bf(acc[mm][nn][rr] + bvv[nn]);
            }
            __syncthreads();
            {
                const int row = tid >> 1, dh = (tid & 1) * 64;
                const int t = t0 + row;
                u16* dr = dstb + (((size_t)(bb * NHEAD + h0 + hh)) * TSEQ + t) * HDIM + dh;
                u16 vals[64];
#pragma unroll
                for (int qq = 0; qq < 8; ++qq)
                    *(short8*)(vals + qq * 8) = *(const short8*)(epi + row * 136 + dh + qq * 8);
                float csv[32], snv[32];
#pragma unroll
                for (int qq = 0; qq < 8; ++qq) {
                    *(float4*)(csv + qq * 4) =
                        *(const float4*)(cosp + (size_t)t * 64 + (dh >> 1) + qq * 4);
                    *(float4*)(snv + qq * 4) =
                        *(const float4*)(sinp + (size_t)t * 64 + (dh >> 1) + qq * 4);
                }
                u16 ov[64];
#pragma unroll
                for (int pp = 0; pp < 32; ++pp) {
                    float x0 = b2f(vals[2 * pp]), x1 = b2f(vals[2 * pp + 1]);
                    ov[2 * pp] = f2bf(x0 * csv[pp] - x1 * snv[pp]);
                    ov[2 * pp + 1] = f2bf(x0 * snv[pp] + x1 * csv[pp]);
                }
#pragma unroll
                for (int qq = 0; qq < 8; ++qq)
                    *(short8*)(dr + qq * 8) = *(const short8*)(ov + qq * 8);
            }
            __syncthreads();
        }
    } else {
        // v: write transposed [bh][d][t]. epi tile [128 d][264 (256 t + pad)] per head-half.
        u16* epi = sm;
#pragma unroll
        for (int hh = 0; hh < 2; ++hh) {
            if ((wc >> 1) == hh) {
#pragma unroll
                for (int mm = 0; mm < 8; ++mm)
#pragma unroll
                    for (int nn = 0; nn < 4; ++nn)
#pragma unroll
                        for (int rr = 0; rr < 4; ++rr)
                            epi[((wc & 1) * 64 + nn * 16 + low) * 264 +
                                wr * 128 + mm * 16 + quad * 4 + rr] = f2bf(acc[mm][nn][rr] + bvv[nn]);
            }
            __syncthreads();
            {
                const int dd = tid >> 2, tc = (tid & 3) * 64;
                u16* dr = vT + ((size_t)(bb * NHEAD + h0 + hh) * HDIM + dd) * TSEQ + t0 + tc;
#pragma unroll
                for (int qq = 0; qq < 8; ++qq)
                    *(short8*)(dr + qq * 8) = *(const short8*)(epi + dd * 264 + tc + qq * 8);
            }
            __syncthreads();
        }
    }
}

// ---------------- proj GEMM: out(f32) = y(bf16) @ WpT(bf16) + bias ----------------
// 128x256 tile, BK=64, 8 waves 2M x 4N (64x64/wave). Grid 32x8 = 256 blocks = 1/CU exact.
#define PMFQ(NB)                                                                                      \
    {                                                                                                 \
        _Pragma("unroll") for (int mm = 0; mm < 4; ++mm) _Pragma("unroll") for (int nn = 0; nn < 2;   \
                                                                                ++nn) {               \
            acc[mm][(NB) + nn] = __builtin_amdgcn_mfma_f32_16x16x32_bf16(                             \
                a[mm][0], b[(NB) + nn][0], acc[mm][(NB) + nn], 0, 0, 0);                              \
            acc[mm][(NB) + nn] = __builtin_amdgcn_mfma_f32_16x16x32_bf16(                             \
                a[mm][1], b[(NB) + nn][1], acc[mm][(NB) + nn], 0, 0, 0);                              \
        }                                                                                             \
    }
#define PPRIO_MFQ(NB)                   \
    {                                   \
        __builtin_amdgcn_s_setprio(1);  \
        PMFQ(NB);                       \
        __builtin_amdgcn_s_setprio(0);  \
    }

__global__ __launch_bounds__(512, 2) void pgemm(
    const u16* __restrict__ A, const u16* __restrict__ Bt, const float* __restrict__ bias,
    float* __restrict__ outf, int M, int N, int K) {
    extern __shared__ u16 sm[];
    u16* const smA0 = sm;             // 128x64
    u16* const smB0 = sm + 8192;      // 256x64
    u16* const smA1 = sm + 24576;
    u16* const smB1 = sm + 32768;     // total 49152 u16 = 96 KiB

    const int tid = threadIdx.x;
    const int wave = tid >> 6, lane = tid & 63;
    const int low = lane & 15, quad = lane >> 4;
    const int wr = wave >> 2, wc = wave & 3;
    const int m0 = blockIdx.y * 128, n0 = blockIdx.x * 256;
    const int NT = K >> 6;

    const int grow = lane >> 3;
    const int gslot = (lane & 7) ^ grow;

    const int swz = low & 7;
    const int arow = (wr * 64 + low) * 64;
    const int brow = (wc * 64 + low) * 64;
    const int aoff0 = arow + ((0 + quad) ^ swz) * 8;
    const int aoff1 = arow + ((4 + quad) ^ swz) * 8;
    const int boff0 = brow + ((0 + quad) ^ swz) * 8;
    const int boff1 = brow + ((4 + quad) ^ swz) * 8;

    f32x4 acc[4][4];
#pragma unroll
    for (int i = 0; i < 4; i++)
#pragma unroll
        for (int j = 0; j < 4; j++) acc[i][j] = zero4();
    short8 a[4][2], b[4][2];

    // ---- prologue: tile0 -> buf0 (6 loads/thread), tile1 -> buf1 (6) ----
    STAGE(A, m0, smA0, 0);
    STAGE(Bt, n0, smB0, 0);
    STAGE(Bt, n0 + 128, smB0 + 8192, 0);
    STAGE(A, m0, smA1, 1);
    STAGE(Bt, n0, smB1, 1);
    STAGE(Bt, n0 + 128, smB1 + 8192, 1);
    VBAR(6);  // tile0 landed; tile1 (6) in flight

    const int NI = (NT >> 1) - 1;
#pragma unroll 1
    for (int it = 0; it < NI; ++it) {
        const int e = it * 2;
        // ---- K-tile e (buf0) ----
        LDA4(smA0, 0);
        LDB2(smB0, 0);
        LDB2(smB0, 2);
        PPRIO_MFQ(0);
        WAIT_DS();
        BAR();  // all buf0 reads retired -> restage buf0
        STAGE(A, m0, smA0, e + 2);
        STAGE(Bt, n0, smB0, e + 2);
        STAGE(Bt, n0 + 128, smB0 + 8192, e + 2);
        PPRIO_MFQ(2);
        VBAR(6);  // drain tile e+1 (6, staged last iter); e+2's 6 in flight
        // ---- K-tile e+1 (buf1) ----
        LDA4(smA1, 0);
        LDB2(smB1, 0);
        LDB2(smB1, 2);
        PPRIO_MFQ(0);
        WAIT_DS();
        BAR();
        STAGE(A, m0, smA1, e + 3);
        STAGE(Bt, n0, smB1, e + 3);
        STAGE(Bt, n0 + 128, smB1 + 8192, e + 3);
        PPRIO_MFQ(2);
        VBAR(6);  // drain tile e+2; e+3's 6 in flight
    }
    // ---- peeled last pair: no stages ----
    LDA4(smA0, 0);
    LDB2(smB0, 0);
    LDB2(smB0, 2);
    PPRIO_MFQ(0);
    PPRIO_MFQ(2);
    VBAR(0);  // drain tile NT-1 before reading buf1
    LDA4(smA1, 0);
    LDB2(smB1, 0);
    LDB2(smB1, 2);
    PPRIO_MFQ(0);
    PPRIO_MFQ(2);

    // ---- epilogue: direct coalesced f32 stores ----
    float bvv[4];
#pragma unroll
    for (int nn = 0; nn < 4; ++nn) bvv[nn] = bias[n0 + wc * 64 + nn * 16 + low];
#pragma unroll
    for (int mm = 0; mm < 4; ++mm) {
        const int rbase = m0 + wr * 64 + mm * 16 + quad * 4;
#pragma unroll
        for (int nn = 0; nn < 4; ++nn) {
            const int col = n0 + wc * 64 + nn * 16 + low;
#pragma unroll
            for (int r = 0; r < 4; ++r)
                outf[(size_t)(rbase + r) * N + col] = acc[mm][nn][r] + bvv[nn];
        }
    }
}

// ---------------- Flash attention: QBLK=128 (8 waves x 16q), dbuf K/V, DPP softmax --------------
// One block covers 128 q-rows -> K/V staged once per 128 rows (traffic halved vs QBLK=64).
// R7 FIX (m104): each async16 issue maps lanes to one LINEAR 1KiB LDS region
// (base + lane*16B). Per wave w, issue q in {0,1}: chunk-block blk = q*8+w.
//   K: row = blk*4 + (lane>>4), slot = lane&15; LDS = Ksb + SEL*8192 + blk*512 + lane*8.
//   V: d   = blk*8 + (lane>>3), slot = lane&7;  LDS = Vsb + SEL*8192 + blk*512 + lane*8.
// Global source carries the XOR swizzle per-lane (source IS per-lane). Readers unchanged:
// LDS slot s of row r holds global chunk s^(r&7).
// Hazard ledger: stage at iter kt targets buf[(kt+1)&1]; its last ds_reads (iter kt-1)
// retired before each wave's arrival at iter-kt's vmcnt(0)+barrier; writes follow it.
#define STAGE_KV(KT, SEL)                                                                   \
    {                                                                                       \
        const int kv0s = (KT) * 64;                                                         \
        _Pragma("unroll") for (int q = 0; q < 2; q++) {                                     \
            const int blk = q * 8 + wave;                                                   \
            const int kr = blk * 4 + (lane >> 4);                                           \
            const int kgc = (lane & 15) ^ (kr & 7);                                         \
            async16(Kb + (size_t)(kv0s + kr) * HDIM + kgc * 8,                              \
                    Ksb + (SEL)*8192 + blk * 512 + lane * 8);                               \
        }                                                                                   \
        _Pragma("unroll") for (int q = 0; q < 2; q++) {                                     \
            const int blk = q * 8 + wave;                                                   \
            const int dv = blk * 8 + (lane >> 3);                                           \
            const int vgc = (lane & 7) ^ (dv & 7);                                          \
            async16(Vb + (size_t)dv * TSEQ + kv0s + vgc * 8,                                \
                    Vsb + (SEL)*8192 + blk * 512 + lane * 8);                               \
        }                                                                                   \
    }

__global__ __launch_bounds__(512, 2) void flash_attn(const u16* __restrict__ qb, const u16* __restrict__ kb,
                                                     const u16* __restrict__ vT, u16* __restrict__ y) {
    extern __shared__ u16 fsm[];
    u16* const Ksb = fsm;               // [2][64*128] keys, chunks xor-swizzled by (key&7)
    u16* const Vsb = fsm + 16384;       // [2][128*64] values, chunks xor-swizzled by (d&7)
    u16* const Psb = fsm + 32768;       // [8][16*72] per-wave P
    const int tid = threadIdx.x;
    const int wave = tid >> 6, lane = tid & 63;
    const int low = lane & 15, quad = lane >> 4;
    const int bh = blockIdx.x;
    const int qt = 15 - blockIdx.y;          // 128-row q blocks, longest first
    const int q0 = qt * 128 + wave * 16;
    const float scale2 = 0.08838834764831845f * 1.44269504088896f;  // 1/sqrt(128) * log2(e)

    const u16* Qp = qb + ((size_t)bh * TSEQ + q0) * HDIM;
    short8 qf[4];
#pragma unroll
    for (int c = 0; c < 4; c++) qf[c] = *(const short8*)(Qp + (size_t)low * HDIM + c * 32 + quad * 8);

    f32x4 o[8];
#pragma unroll
    for (int d = 0; d < 8; d++) o[d] = zero4();
    float m_i[4], l_i[4];
#pragma unroll
    for (int r = 0; r < 4; r++) { m_i[r] = -1e30f; l_i[r] = 0.f; }

    const u16* Kb = kb + (size_t)bh * TSEQ * HDIM;
    const u16* Vb = vT + (size_t)bh * HDIM * TSEQ;
    u16* Pw = Psb + wave * 1152;
    const int ntiles = 2 * qt + 2;

    STAGE_KV(0, 0);
    for (int kt = 0; kt < ntiles; ++kt) {
        const int kv0 = kt * 64;
        VBAR(0);  // tile kt landed (all waves); prior reads of the other buffer retired
        if (kt + 1 < ntiles) STAGE_KV(kt + 1, (kt + 1) & 1);
        const u16* Kc = Ksb + (kt & 1) * 8192;
        const u16* Vc = Vsb + (kt & 1) * 8192;

        if (kv0 <= q0 + 15) {  // wave-uniform: skip fully-masked tiles
            // ---- QK^T: S[16q x 64k] ----
            f32x4 s[4];
#pragma unroll
            for (int h = 0; h < 4; h++) s[h] = zero4();
            __builtin_amdgcn_s_setprio(1);
#pragma unroll
            for (int h = 0; h < 4; h++) {
                const int row = h * 16 + low;
#pragma unroll
                for (int c = 0; c < 4; c++) {
                    const int cc = c * 4 + quad;
                    short8 kf = *(const short8*)(Kc + row * 128 + (cc ^ (row & 7)) * 8);
                    s[h] = __builtin_amdgcn_mfma_f32_16x16x32_bf16(qf[c], kf, s[h], 0, 0, 0);
                }
            }
            __builtin_amdgcn_s_setprio(0);

            // ---- online softmax (exp2 domain); mask only near-diagonal tiles ----
            const bool domask = (kv0 + 63 > q0);
            float alpha[4];
#pragma unroll
            for (int r = 0; r < 4; r++) {
                const int qg = q0 + quad * 4 + r;
                float sv[4];
#pragma unroll
                for (int h = 0; h < 4; h++) sv[h] = s[h][r] * scale2;
                if (domask) {
#pragma unroll
                    for (int h = 0; h < 4; h++)
                        if (kv0 + h * 16 + low > qg) sv[h] = -1e30f;
                }
                float mx = fmaxf(fmaxf(sv[0], sv[1]), fmaxf(sv[2], sv[3]));
                mx = dpp_max16(mx);
                float mnew = fmaxf(m_i[r], mx);
                alpha[r] = exp2f(m_i[r] - mnew);
                m_i[r] = mnew;
                float p0 = exp2f(sv[0] - mnew);
                float p1 = exp2f(sv[1] - mnew);
                float p2 = exp2f(sv[2] - mnew);
                float p3 = exp2f(sv[3] - mnew);
                float rs = (p0 + p1) + (p2 + p3);
                rs = dpp_sum16(rs);
                l_i[r] = l_i[r] * alpha[r] + rs;
                const int prow = (quad * 4 + r) * 72;
                Pw[prow + low] = f2bf(p0);
                Pw[prow + 16 + low] = f2bf(p1);
                Pw[prow + 32 + low] = f2bf(p2);
                Pw[prow + 48 + low] = f2bf(p3);
            }
            __threadfence_block();

#pragma unroll
            for (int d = 0; d < 8; ++d)
#pragma unroll
                for (int r = 0; r < 4; r++) o[d][r] *= alpha[r];

            // ---- PV ----
            __builtin_amdgcn_s_setprio(1);
#pragma unroll
            for (int kc = 0; kc < 2; kc++) {
                short8 pf = *(const short8*)(Pw + low * 72 + kc * 32 + quad * 8);
#pragma unroll
                for (int dd = 0; dd < 8; ++dd) {
                    const int vr = dd * 16 + low;
                    const int cc = kc * 4 + quad;
                    short8 vf = *(const short8*)(Vc + vr * 64 + (cc ^ (vr & 7)) * 8);
                    o[dd] = __builtin_amdgcn_mfma_f32_16x16x32_bf16(pf, vf, o[dd], 0, 0, 0);
                }
            }
            __builtin_amdgcn_s_setprio(0);
        }
    }

    const int b = bh >> 4, h = bh & 15;
#pragma unroll
    for (int r = 0; r < 4; r++) {
        float inv = 1.0f / l_i[r];
        size_t row = (size_t)(b * TSEQ + q0 + quad * 4 + r);
        u16* yp = y + row * 2048 + h * HDIM;
#pragma unroll
        for (int d = 0; d < 8; ++d) yp[d * 16 + low] = f2bf(o[d][r] * inv);
    }
}

extern "C" void kernel_launch(void* const* d_in, const int* in_sizes, int n_in,
                              void* d_out, int out_size, void* d_ws, size_t ws_size,
                              hipStream_t stream) {
    const float* x = (const float*)d_in[0];
    const float* Wa = (const float*)d_in[1];
    const float* ba = (const float*)d_in[2];
    const float* Wp = (const float*)d_in[3];
    const float* bp = (const float*)d_in[4];
    const float* cs = (const float*)d_in[5];
    const float* sn = (const float*)d_in[6];
    float* out = (float*)d_out;

    u16* xb = (u16*)d_ws;             // x bf16; reused later as y
    u16* Wab = xb + 8388608;          // W_attn^T bf16 [6144][2048]
    u16* Wpb = Wab + 12582912;        // W_proj^T bf16 [2048][2048]
    u16* qb = Wpb + 4194304;          // [bh][t][d]
    u16* kb = qb + 8388608;           // [bh][t][d]
    u16* vT = kb + 8388608;           // [bh][d][t]
    u16* y = xb;

    static bool attr_set = false;
    if (!attr_set) {
        hipFuncSetAttribute(reinterpret_cast<const void*>(gemm256),
                            hipFuncAttributeMaxDynamicSharedMemorySize, 131072);
        hipFuncSetAttribute(reinterpret_cast<const void*>(pgemm),
                            hipFuncAttributeMaxDynamicSharedMemorySize, 98304);
        hipFuncSetAttribute(reinterpret_cast<const void*>(flash_attn),
                            hipFuncAttributeMaxDynamicSharedMemorySize, 83968);
        attr_set = true;
    }

    prep<<<12288, 256, 0, stream>>>(x, xb, Wa, Wab, Wp, Wpb);
    gemm256<<<dim3(24, 16), 512, 131072, stream>>>(xb, Wab, ba, qb, kb, vT, cs, sn, 4096, 6144, 2048);
    flash_attn<<<dim3(32, 16), 512, 83968, stream>>>(qb, kb, vT, y);
    pgemm<<<dim3(8, 32), 512, 98304, stream>>>(y, Wpb, bp, out, 4096, 2048, 2048);
}